// Round 1
// baseline (563.183 us; speedup 1.0000x reference)
//
#include <hip/hip_runtime.h>

#define NH 128
#define SLOTS 16          // 512 threads = 16 half-wave (32-lane) row slots
#define PF 5              // prefetched logit rows per slot (covers tot <= 80)

// ---------------------------------------------------------------------------
// K1: block 0 = exclusive scan of grid_sizes -> c[0..G]; blocks 1..16 = matA
//     A = Wk @ Wi,  u = Wk @ bi
// ---------------------------------------------------------------------------
__global__ void setup1_kernel(const int* __restrict__ gs, int* __restrict__ c, int G,
                              const float* __restrict__ Wk, const float* __restrict__ Wi,
                              const float* __restrict__ bi,
                              float* __restrict__ A, float* __restrict__ u) {
    if (blockIdx.x == 0) {
        __shared__ int part[1024];
        int t = threadIdx.x;
        int chunk = (G + 1023) >> 10;
        int b = t * chunk;
        int e = min(b + chunk, G);
        int s = 0;
        for (int i = b; i < e; ++i) s += gs[i];
        part[t] = s;
        __syncthreads();
        for (int off = 1; off < 1024; off <<= 1) {
            int val = (t >= off) ? part[t - off] : 0;
            __syncthreads();
            part[t] += val;
            __syncthreads();
        }
        int excl = (t == 0) ? 0 : part[t - 1];
        for (int i = b; i < e; ++i) { c[i] = excl; excl += gs[i]; }
        if (t == 1023) c[G] = part[1023];
    } else {
        int tid = (blockIdx.x - 1) * 1024 + threadIdx.x;   // 0..NH*NH-1
        int e = tid >> 7, d = tid & (NH - 1);
        float acc = 0.f;
        for (int f = 0; f < NH; ++f) acc += Wk[e * NH + f] * Wi[f * NH + d];
        A[e * NH + d] = acc;
        if (tid < NH) {
            float s = 0.f;
            for (int f = 0; f < NH; ++f) s += Wk[tid * NH + f] * bi[f];
            u[tid] = s;
        }
    }
}

// ---------------------------------------------------------------------------
// K2: Bt[f*NH+d] = sum_e Wi[e,d]*A[e,f];  v = Wi^T u;  w[f] = bi.A[:,f];
//     s0 = bi.u + bk
// ---------------------------------------------------------------------------
__global__ void matB_kernel(const float* __restrict__ Wi, const float* __restrict__ bi,
                            const float* __restrict__ bk,
                            const float* __restrict__ A, const float* __restrict__ u,
                            float* __restrict__ Bt, float* __restrict__ v,
                            float* __restrict__ w, float* __restrict__ s0) {
    int tid = blockIdx.x * blockDim.x + threadIdx.x;
    int i = tid & (NH - 1);
    int j = tid >> 7;
    float acc = 0.f;
    for (int e = 0; e < NH; ++e) acc += Wi[e * NH + i] * A[e * NH + j];
    Bt[j * NH + i] = acc;
    if (tid < NH) {
        float s = 0.f;
        for (int e = 0; e < NH; ++e) s += Wi[e * NH + tid] * u[e];
        v[tid] = s;
    } else if (tid < 2 * NH) {
        int jj = tid - NH;
        float s = 0.f;
        for (int e = 0; e < NH; ++e) s += bi[e] * A[e * NH + jj];
        w[jj] = s;
    }
    if (tid == 0) {
        float s = 0.f;
        for (int e = 0; e < NH; ++e) s += bi[e] * u[e];
        s0[0] = s + bk[0];
    }
}

// ---------------------------------------------------------------------------
// K3: mega kernel — one block per segment, 512 threads:
//   phase 1: M[g] = mean over pos rows of embedding_          (16-slot gather)
//   phase 3a: prefetch this segment's logit rows into registers
//   phase 2: q = Bt^T m + v,  c2 = w.m + s0  (L2-resident matvec hides 3a)
//   phase 3b: out = row . q + c2 for pos and neg samples
// ---------------------------------------------------------------------------
__global__ __launch_bounds__(512, 6)
void mega_kernel(const float* __restrict__ emb, const float* __restrict__ emb_,
                 const int* __restrict__ pos, const int* __restrict__ neg,
                 const int* __restrict__ c, const float* __restrict__ Bt,
                 const float* __restrict__ v, const float* __restrict__ w,
                 const float* __restrict__ s0, float* __restrict__ out,
                 int P, int ratio) {
    __shared__ float smf[SLOTS * NH];   // 8 KB partial sums
    __shared__ float m[NH];
    __shared__ float qp[4][NH];
    __shared__ float qs[NH];
    __shared__ float redc[2];

    int g = blockIdx.x;
    int t = threadIdx.x;
    int lane = t & 31, slot = t >> 5;

    int pb = c[g], pe = c[g + 1];
    int np = pe - pb;
    int nb = pb * ratio;
    int tot = np + np * ratio;

    // ---- phase 1: segment mean of raw embedding_ rows ----
    float4 acc = make_float4(0.f, 0.f, 0.f, 0.f);
    for (int r = pb + slot; r < pe; r += SLOTS) {
        int row = pos[r];
        const float4 a = ((const float4*)(emb_ + (size_t)row * NH))[lane];
        acc.x += a.x; acc.y += a.y; acc.z += a.z; acc.w += a.w;
    }
    ((float4*)(smf + slot * NH))[lane] = acc;
    __syncthreads();
    if (t < NH) {
        float s = 0.f;
#pragma unroll
        for (int k = 0; k < SLOTS; ++k) s += smf[k * NH + t];
        m[t] = s / (float)max(np, 1);
    }
    __syncthreads();

    // ---- phase 3a: prefetch logit rows (independent of q) ----
    float4 areg[PF];
#pragma unroll
    for (int i = 0; i < PF; ++i) {
        int kk = slot + i * SLOTS;
        if (kk < tot) {
            int row = (kk < np) ? pos[pb + kk] : neg[nb + kk - np];
            areg[i] = ((const float4*)(emb + (size_t)row * NH))[lane];
        }
    }

    // ---- phase 2: q[d] = sum_f Bt[f*NH+d] * m[f]  (4-way f-split) ----
    {
        int d = t & (NH - 1);
        int quarter = t >> 7;          // 0..3
        int f0 = quarter * 32;
        float p = 0.f;
#pragma unroll 8
        for (int f = f0; f < f0 + 32; ++f) p += Bt[f * NH + d] * m[f];
        qp[quarter][d] = p;
    }
    __syncthreads();
    if (t < NH) {
        qs[t] = qp[0][t] + qp[1][t] + qp[2][t] + qp[3][t] + v[t];
        float val = w[t] * m[t];
#pragma unroll
        for (int off = 32; off; off >>= 1) val += __shfl_xor(val, off, 64);
        if ((t & 63) == 0) redc[t >> 6] = val;
    }
    __syncthreads();
    float c2 = redc[0] + redc[1] + s0[0];
    float4 qr = ((const float4*)qs)[lane];

    // ---- phase 3b: dot + reduce + store (4-5 independent chains) ----
#pragma unroll
    for (int i = 0; i < PF; ++i) {
        int kk = slot + i * SLOTS;
        if (kk < tot) {
            float4 a = areg[i];
            float val = a.x * qr.x + a.y * qr.y + a.z * qr.z + a.w * qr.w;
#pragma unroll
            for (int off = 16; off; off >>= 1) val += __shfl_xor(val, off, 32);
            if (lane == 0) {
                int o = (kk < np) ? (pb + kk) : (P + nb + kk - np);
                out[o] = val + c2;
            }
        }
    }
    // fallback for segments larger than SLOTS*PF rows (not hit at SEG=25)
    for (int kk = slot + PF * SLOTS; kk < tot; kk += SLOTS) {
        int row = (kk < np) ? pos[pb + kk] : neg[nb + kk - np];
        const float4 a = ((const float4*)(emb + (size_t)row * NH))[lane];
        float val = a.x * qr.x + a.y * qr.y + a.z * qr.z + a.w * qr.w;
#pragma unroll
        for (int off = 16; off; off >>= 1) val += __shfl_xor(val, off, 32);
        if (lane == 0) {
            int o = (kk < np) ? (pb + kk) : (P + nb + kk - np);
            out[o] = val + c2;
        }
    }
}

// ---------------------------------------------------------------------------
extern "C" void kernel_launch(void* const* d_in, const int* in_sizes, int n_in,
                              void* d_out, int out_size, void* d_ws, size_t ws_size,
                              hipStream_t stream) {
    const float* embedding  = (const float*)d_in[0];
    const float* embedding_ = (const float*)d_in[1];
    const int*   grid_sizes = (const int*)d_in[2];
    const int*   pos        = (const int*)d_in[3];
    const int*   neg        = (const int*)d_in[4];
    const float* Wi         = (const float*)d_in[5];
    const float* bi         = (const float*)d_in[6];
    const float* Wk         = (const float*)d_in[7];
    const float* bk         = (const float*)d_in[8];

    int G = in_sizes[2];
    int P = in_sizes[3];
    int PN = in_sizes[4];
    int ratio = PN / P;

    char* ws = (char*)d_ws;
    size_t off = 0;
    auto alloc = [&](size_t bytes) {
        void* p = ws + off;
        off += (bytes + 255) & ~(size_t)255;
        return p;
    };
    int*   c   = (int*)  alloc((size_t)(G + 1) * sizeof(int));
    float* A   = (float*)alloc(NH * NH * sizeof(float));
    float* u   = (float*)alloc(NH * sizeof(float));
    float* Bt  = (float*)alloc(NH * NH * sizeof(float));
    float* v   = (float*)alloc(NH * sizeof(float));
    float* w   = (float*)alloc(NH * sizeof(float));
    float* s0  = (float*)alloc(sizeof(float));
    (void)ws_size; (void)n_in; (void)out_size;

    // K1: scan (block 0) + matA (blocks 1..16)
    hipLaunchKernelGGL(setup1_kernel, dim3(1 + (NH * NH) / 1024), dim3(1024), 0, stream,
                       grid_sizes, c, G, Wk, Wi, bi, A, u);
    // K2: Bt, v, w, s0
    hipLaunchKernelGGL(matB_kernel, dim3((NH * NH) / 256), dim3(256), 0, stream,
                       Wi, bi, bk, A, u, Bt, v, w, s0);
    // K3: fused seg_mean + q + logits
    hipLaunchKernelGGL(mega_kernel, dim3(G), dim3(512), 0, stream,
                       embedding, embedding_, pos, neg, c, Bt, v, w, s0,
                       (float*)d_out, P, ratio);
}

// Round 2
// 528.468 us; speedup vs baseline: 1.0657x; 1.0657x over previous
//
#include <hip/hip_runtime.h>

#define NH 128

// ---------------------------------------------------------------------------
// K1: block 0 = exclusive scan of grid_sizes -> c[0..G]; blocks 1..16 = matA
//     A = Wk @ Wi,  u = Wk @ bi
// ---------------------------------------------------------------------------
__global__ void setup1_kernel(const int* __restrict__ gs, int* __restrict__ c, int G,
                              const float* __restrict__ Wk, const float* __restrict__ Wi,
                              const float* __restrict__ bi,
                              float* __restrict__ A, float* __restrict__ u) {
    if (blockIdx.x == 0) {
        __shared__ int part[1024];
        int t = threadIdx.x;
        int chunk = (G + 1023) >> 10;
        int b = t * chunk;
        int e = min(b + chunk, G);
        int s = 0;
        for (int i = b; i < e; ++i) s += gs[i];
        part[t] = s;
        __syncthreads();
        for (int off = 1; off < 1024; off <<= 1) {
            int val = (t >= off) ? part[t - off] : 0;
            __syncthreads();
            part[t] += val;
            __syncthreads();
        }
        int excl = (t == 0) ? 0 : part[t - 1];
        for (int i = b; i < e; ++i) { c[i] = excl; excl += gs[i]; }
        if (t == 1023) c[G] = part[1023];
    } else {
        int tid = (blockIdx.x - 1) * 1024 + threadIdx.x;   // 0..NH*NH-1
        int e = tid >> 7, d = tid & (NH - 1);
        float acc = 0.f;
        for (int f = 0; f < NH; ++f) acc += Wk[e * NH + f] * Wi[f * NH + d];
        A[e * NH + d] = acc;
        if (tid < NH) {
            float s = 0.f;
            for (int f = 0; f < NH; ++f) s += Wk[tid * NH + f] * bi[f];
            u[tid] = s;
        }
    }
}

// ---------------------------------------------------------------------------
// K2: Bt[f*NH+d] = sum_e Wi[e,d]*A[e,f];  v = Wi^T u;  w[f] = bi.A[:,f];
//     s0 = bi.u + bk
// ---------------------------------------------------------------------------
__global__ void matB_kernel(const float* __restrict__ Wi, const float* __restrict__ bi,
                            const float* __restrict__ bk,
                            const float* __restrict__ A, const float* __restrict__ u,
                            float* __restrict__ Bt, float* __restrict__ v,
                            float* __restrict__ w, float* __restrict__ s0) {
    int tid = blockIdx.x * blockDim.x + threadIdx.x;
    int i = tid & (NH - 1);
    int j = tid >> 7;
    float acc = 0.f;
    for (int e = 0; e < NH; ++e) acc += Wi[e * NH + i] * A[e * NH + j];
    Bt[j * NH + i] = acc;
    if (tid < NH) {
        float s = 0.f;
        for (int e = 0; e < NH; ++e) s += Wi[e * NH + tid] * u[e];
        v[tid] = s;
    } else if (tid < 2 * NH) {
        int jj = tid - NH;
        float s = 0.f;
        for (int e = 0; e < NH; ++e) s += bi[e] * A[e * NH + jj];
        w[jj] = s;
    }
    if (tid == 0) {
        float s = 0.f;
        for (int e = 0; e < NH; ++e) s += bi[e] * u[e];
        s0[0] = s + bk[0];
    }
}

// ---------------------------------------------------------------------------
// K3: seg_mean — ONE 64-LANE WAVE PER SEGMENT, no LDS, no barriers.
//     Lane owns 2 columns (float2). 8-row chunks -> 8 independent 512B row
//     loads in flight per wave. Also writes segid[r] = g for each pos sample.
// ---------------------------------------------------------------------------
#define MCH 8
__global__ __launch_bounds__(256, 8)
void seg_mean_kernel(const float* __restrict__ emb_, const int* __restrict__ pos,
                     const int* __restrict__ c, float* __restrict__ M,
                     int* __restrict__ segid, int G) {
    int wave  = (blockIdx.x * blockDim.x + threadIdx.x) >> 6;
    int lane  = threadIdx.x & 63;
    int nwave = (gridDim.x * blockDim.x) >> 6;
    for (int g = wave; g < G; g += nwave) {
        int pb = c[g], pe = c[g + 1];
        int np = pe - pb;
        float2 acc = make_float2(0.f, 0.f);
        for (int r0 = 0; r0 < np; r0 += 64) {
            int nr = min(64, np - r0);
            int idxv = 0;
            if (lane < nr) {
                idxv = pos[pb + r0 + lane];
                segid[pb + r0 + lane] = g;
            }
            int r = 0;
            for (; r + MCH <= nr; r += MCH) {
                float2 a[MCH];
#pragma unroll
                for (int j = 0; j < MCH; ++j) {
                    int row = __shfl(idxv, r + j, 64);
                    a[j] = ((const float2*)(emb_ + (size_t)row * NH))[lane];
                }
#pragma unroll
                for (int j = 0; j < MCH; ++j) { acc.x += a[j].x; acc.y += a[j].y; }
            }
            for (; r < nr; ++r) {
                int row = __shfl(idxv, r, 64);
                float2 a = ((const float2*)(emb_ + (size_t)row * NH))[lane];
                acc.x += a.x; acc.y += a.y;
            }
        }
        float cnt = (float)max(np, 1);
        ((float2*)(M + (size_t)g * NH))[lane] = make_float2(acc.x / cnt, acc.y / cnt);
    }
}

// ---------------------------------------------------------------------------
// K4: q_kernel: Q[g] = B @ M[g] + v ; C2[g] = w . M[g] + s0   (8 segs / block)
// ---------------------------------------------------------------------------
#define SPB 8
__global__ void q_kernel(const float* __restrict__ M, const float* __restrict__ Bt,
                         const float* __restrict__ v, const float* __restrict__ w,
                         const float* __restrict__ s0,
                         float* __restrict__ Q, float* __restrict__ C2, int G) {
    __shared__ float m[SPB][NH];
    __shared__ float red[SPB][2];
    int d = threadIdx.x;            // 128
    int g0 = blockIdx.x * SPB;
    int ns = min(SPB, G - g0);
    for (int s = 0; s < SPB; ++s)
        m[s][d] = (s < ns) ? M[(size_t)(g0 + s) * NH + d] : 0.f;
    __syncthreads();

    float q[SPB];
#pragma unroll
    for (int s = 0; s < SPB; ++s) q[s] = 0.f;
    for (int f = 0; f < NH; ++f) {
        float bt = Bt[f * NH + d];
#pragma unroll
        for (int s = 0; s < SPB; ++s) q[s] += bt * m[s][f];
    }
    float vd = v[d], wd = w[d], s00 = s0[0];
    for (int s = 0; s < ns; ++s)
        Q[(size_t)(g0 + s) * NH + d] = q[s] + vd;

    int lane = d & 63, wv = d >> 6;
    for (int s = 0; s < SPB; ++s) {
        float tval = wd * m[s][d];
        for (int off = 32; off; off >>= 1) tval += __shfl_xor(tval, off);
        if (lane == 0) red[s][wv] = tval;
    }
    __syncthreads();
    if (d < SPB && d < ns) C2[g0 + d] = red[d][0] + red[d][1] + s00;
}

// ---------------------------------------------------------------------------
// K5: logits — FLAT grid-stride, 32-lane group per sample, U=4 unroll,
//     no LDS, no barriers. sid comes from segid[] (pos) or segid[j/ratio]
//     (neg, via 2^42 magic division).  out[k] = emb[row].Q[sid] + C2[sid]
// ---------------------------------------------------------------------------
#define U 4
__global__ __launch_bounds__(256, 6)
void logits_kernel(const float* __restrict__ emb, const int* __restrict__ pos,
                   const int* __restrict__ neg, const int* __restrict__ segid,
                   const float* __restrict__ Q, const float* __restrict__ C2,
                   float* __restrict__ out, int P, int PN,
                   unsigned long long magic) {
    int tot = P + PN;
    int gid  = (blockIdx.x * blockDim.x + threadIdx.x) >> 5;
    int lane = threadIdx.x & 31;
    int ngrp = (gridDim.x * blockDim.x) >> 5;
    long long stride = (long long)ngrp * U;

    for (long long base = (long long)gid * U; base < tot; base += stride) {
        int kk[U], row[U], sid[U];
#pragma unroll
        for (int j = 0; j < U; ++j) {
            int k = (int)base + j;
            int k2 = (k < tot) ? k : (tot - 1);
            kk[j] = k2;
            if (k2 < P) {
                row[j] = pos[k2];
                sid[j] = segid[k2];
            } else {
                int jn = k2 - P;
                row[j] = neg[jn];
                int jp = (int)(((unsigned long long)(unsigned)jn * magic) >> 42);
                sid[j] = segid[jp];
            }
        }
        float4 a[U], q[U];
        float c2v[U];
#pragma unroll
        for (int j = 0; j < U; ++j) {
            a[j]   = ((const float4*)(emb + (size_t)row[j] * NH))[lane];
            q[j]   = ((const float4*)(Q   + (size_t)sid[j] * NH))[lane];
            c2v[j] = C2[sid[j]];
        }
#pragma unroll
        for (int j = 0; j < U; ++j) {
            float val = a[j].x * q[j].x + a[j].y * q[j].y
                      + a[j].z * q[j].z + a[j].w * q[j].w;
#pragma unroll
            for (int off = 16; off; off >>= 1) val += __shfl_xor(val, off, 32);
            if (lane == 0 && base + j < tot) out[kk[j]] = val + c2v[j];
        }
    }
}

// ---------------------------------------------------------------------------
extern "C" void kernel_launch(void* const* d_in, const int* in_sizes, int n_in,
                              void* d_out, int out_size, void* d_ws, size_t ws_size,
                              hipStream_t stream) {
    const float* embedding  = (const float*)d_in[0];
    const float* embedding_ = (const float*)d_in[1];
    const int*   grid_sizes = (const int*)d_in[2];
    const int*   pos        = (const int*)d_in[3];
    const int*   neg        = (const int*)d_in[4];
    const float* Wi         = (const float*)d_in[5];
    const float* bi         = (const float*)d_in[6];
    const float* Wk         = (const float*)d_in[7];
    const float* bk         = (const float*)d_in[8];

    int G = in_sizes[2];
    int P = in_sizes[3];
    int PN = in_sizes[4];
    int ratio = (P > 0) ? (PN / P) : 1;
    if (ratio < 1) ratio = 1;
    unsigned long long magic = (((unsigned long long)1 << 42) + ratio - 1) / (unsigned long long)ratio;

    char* ws = (char*)d_ws;
    size_t off = 0;
    auto alloc = [&](size_t bytes) {
        void* p = ws + off;
        off += (bytes + 255) & ~(size_t)255;
        return p;
    };
    int*   c     = (int*)  alloc((size_t)(G + 1) * sizeof(int));
    float* A     = (float*)alloc(NH * NH * sizeof(float));
    float* u     = (float*)alloc(NH * sizeof(float));
    float* Bt    = (float*)alloc(NH * NH * sizeof(float));
    float* v     = (float*)alloc(NH * sizeof(float));
    float* w     = (float*)alloc(NH * sizeof(float));
    float* s0    = (float*)alloc(sizeof(float));
    float* M     = (float*)alloc((size_t)G * NH * sizeof(float));
    float* Q     = (float*)alloc((size_t)G * NH * sizeof(float));
    float* C2    = (float*)alloc((size_t)G * sizeof(float));
    int*   segid = (int*)  alloc((size_t)P * sizeof(int));
    (void)ws_size; (void)n_in; (void)out_size;

    // K1: scan (block 0) + matA (blocks 1..16)
    hipLaunchKernelGGL(setup1_kernel, dim3(1 + (NH * NH) / 1024), dim3(1024), 0, stream,
                       grid_sizes, c, G, Wk, Wi, bi, A, u);
    // K2: Bt, v, w, s0
    hipLaunchKernelGGL(matB_kernel, dim3((NH * NH) / 256), dim3(256), 0, stream,
                       Wi, bi, bk, A, u, Bt, v, w, s0);
    // K3: wave-per-segment mean + segid
    int smblocks = (G + 3) / 4;
    hipLaunchKernelGGL(seg_mean_kernel, dim3(smblocks), dim3(256), 0, stream,
                       embedding_, pos, c, M, segid, G);
    // K4: Q, C2
    hipLaunchKernelGGL(q_kernel, dim3((G + SPB - 1) / SPB), dim3(NH), 0, stream,
                       M, Bt, v, w, s0, Q, C2, G);
    // K5: flat logits
    hipLaunchKernelGGL(logits_kernel, dim3(2048), dim3(256), 0, stream,
                       embedding, pos, neg, segid, Q, C2, (float*)d_out, P, PN, magic);
}